// Round 1
// baseline (151.991 us; speedup 1.0000x reference)
//
#include <hip/hip_runtime.h>
#include <math.h>

#define B_   4
#define K_   200
#define DIM_ 256
#define T_   800

__device__ __forceinline__ float silu_f(float x) {
    // x * sigmoid(x) = x / (1 + exp(-x)); correct limits at +-inf
    return x / (1.0f + __expf(-x));
}

// ---------------------------------------------------------------------------
// Kernel A: inclusive scan of durations -> token_start / token_end  [B,K]
// ---------------------------------------------------------------------------
__global__ __launch_bounds__(256) void scan_kernel(
        const float* __restrict__ dur,
        float* __restrict__ starts, float* __restrict__ ends) {
    __shared__ float sc[256];
    const int b = blockIdx.x, tid = threadIdx.x;
    float d = (tid < K_) ? dur[b * K_ + tid] : 0.0f;
    sc[tid] = d;
    __syncthreads();
    for (int off = 1; off < 256; off <<= 1) {
        float v = (tid >= off) ? sc[tid - off] : 0.0f;
        __syncthreads();
        sc[tid] += v;
        __syncthreads();
    }
    if (tid < K_) {
        float e = sc[tid];
        ends[b * K_ + tid]   = e;
        starts[b * K_ + tid] = e - d;
    }
}

// ---------------------------------------------------------------------------
// Kernel B: 3-tap 'SAME' conv over token axis + SiLU -> left/right [B,K,8]
// One block per (b,k); thread = input channel c (DIM_=256).
// ---------------------------------------------------------------------------
__global__ __launch_bounds__(256) void conv_kernel(
        const float* __restrict__ feats,
        const float* __restrict__ w1, const float* __restrict__ b1,
        const float* __restrict__ w2, const float* __restrict__ b2,
        float* __restrict__ left, float* __restrict__ right) {
    const int bk = blockIdx.x;
    const int b = bk / K_, k = bk % K_;
    const int c = threadIdx.x;

    float acc1[8], acc2[8];
#pragma unroll
    for (int o = 0; o < 8; ++o) { acc1[o] = 0.0f; acc2[o] = 0.0f; }

#pragma unroll
    for (int tap = 0; tap < 3; ++tap) {
        int kk = k + tap - 1;
        if (kk < 0 || kk >= K_) continue;   // zero padding
        float x = feats[(b * K_ + kk) * DIM_ + c];
        const float* wp1 = w1 + (tap * DIM_ + c) * 8;
        const float* wp2 = w2 + (tap * DIM_ + c) * 8;
#pragma unroll
        for (int o = 0; o < 8; ++o) {
            acc1[o] += x * wp1[o];
            acc2[o] += x * wp2[o];
        }
    }

    // reduce across the 64-lane wave
#pragma unroll
    for (int o = 0; o < 8; ++o) {
        for (int off = 32; off > 0; off >>= 1) {
            acc1[o] += __shfl_down(acc1[o], off);
            acc2[o] += __shfl_down(acc2[o], off);
        }
    }
    __shared__ float part[4][16];
    const int wave = threadIdx.x >> 6, lane = threadIdx.x & 63;
    if (lane == 0) {
#pragma unroll
        for (int o = 0; o < 8; ++o) {
            part[wave][o]     = acc1[o];
            part[wave][8 + o] = acc2[o];
        }
    }
    __syncthreads();
    if (threadIdx.x < 16) {
        int tid = threadIdx.x;
        float s = part[0][tid] + part[1][tid] + part[2][tid] + part[3][tid];
        int o = tid & 7;
        if (tid < 8) left [(b * K_ + k) * 8 + o] = silu_f(s + b1[o]);
        else         right[(b * K_ + k) * 8 + o] = silu_f(s + b2[o]);
    }
}

// ---------------------------------------------------------------------------
// Main kernel: one block per (t, b). 256 threads.
//   phase 1: threads 0..K-1 compute logits (sw2 path) -> softmax W in LDS
//   phase 2: threads 0..K-1 compute C (sw1 path), store W*C -> reduce A[16]
//   phase 3: thread d computes O[d] + (A @ p2_w)[d] + p2_b[d]
// ---------------------------------------------------------------------------
__global__ __launch_bounds__(256) void main_kernel(
        const float* __restrict__ feats,
        const float* __restrict__ starts, const float* __restrict__ ends,
        const float* __restrict__ left,   const float* __restrict__ right,
        const float* __restrict__ sw1_w1, const float* __restrict__ sw1_b1,
        const float* __restrict__ sw1_w2, const float* __restrict__ sw1_b2,
        const float* __restrict__ sw2_w1, const float* __restrict__ sw2_b1,
        const float* __restrict__ sw2_w2, const float* __restrict__ sw2_b2,
        const float* __restrict__ p1_w,   const float* __restrict__ p1_b,
        const float* __restrict__ p2_w,   const float* __restrict__ p2_b,
        float* __restrict__ out) {
    const int t   = blockIdx.x;
    const int b   = blockIdx.y;
    const int tid = threadIdx.x;

    __shared__ float lw1[160], lb1[16], lw2[256], lb2[16];
    __shared__ float rw1[20], rb1[2], rw2[4], rb2[2], lp1[3];
    __shared__ float wsh[256];       // softmax weights
    __shared__ float red[256];       // reduction scratch
    __shared__ float wc[16 * K_];    // p-major [16][K]  (W[k]*C[k][p])
    __shared__ float aA[16];

    // stage small weights into LDS
    if (tid < 160) lw1[tid] = sw1_w1[tid];
    lw2[tid] = sw1_w2[tid];
    if (tid < 16) { lb1[tid] = sw1_b1[tid]; lb2[tid] = sw1_b2[tid]; }
    if (tid < 20) rw1[tid] = sw2_w1[tid];
    if (tid < 4)  rw2[tid] = sw2_w2[tid];
    if (tid < 2)  { rb1[tid] = sw2_b1[tid]; rb2[tid] = sw2_b2[tid]; }
    if (tid == 0) { lp1[0] = p1_w[0]; lp1[1] = p1_w[1]; lp1[2] = p1_b[0]; }

    float S = 0.0f, E = 0.0f;
    if (tid < K_) {
        float st = starts[b * K_ + tid];
        float en = ends  [b * K_ + tid];
        S = (float)t - st;
        E = en - (float)t;
    }
    __syncthreads();

    // ---- phase 1: logits via sw2 path ----
    float logit = -1e30f;
    if (tid < K_) {
        const float* rf = right + (b * K_ + tid) * 8;
        float h0 = rb1[0] + S * rw1[0] + E * rw1[2];
        float h1 = rb1[1] + S * rw1[1] + E * rw1[3];
#pragma unroll
        for (int i = 0; i < 8; ++i) {
            float f = rf[i];
            h0 += f * rw1[(2 + i) * 2 + 0];
            h1 += f * rw1[(2 + i) * 2 + 1];
        }
        h0 = silu_f(h0); h1 = silu_f(h1);
        float g0 = silu_f(rb2[0] + h0 * rw2[0] + h1 * rw2[2]);
        float g1 = silu_f(rb2[1] + h0 * rw2[1] + h1 * rw2[3]);
        logit = g0 * lp1[0] + g1 * lp1[1] + lp1[2];
    }

    // ---- softmax over K (block reduction) ----
    red[tid] = logit;
    __syncthreads();
    for (int s = 128; s > 0; s >>= 1) {
        if (tid < s) red[tid] = fmaxf(red[tid], red[tid + s]);
        __syncthreads();
    }
    float m = red[0];
    __syncthreads();
    float w = (tid < K_) ? __expf(logit - m) : 0.0f;
    red[tid] = w;
    __syncthreads();
    for (int s = 128; s > 0; s >>= 1) {
        if (tid < s) red[tid] += red[tid + s];
        __syncthreads();
    }
    w = w / red[0];
    wsh[tid] = w;

    // ---- phase 2: C via sw1 path, accumulate W*C ----
    if (tid < K_) {
        const float* lfp = left + (b * K_ + tid) * 8;
        float f[8];
#pragma unroll
        for (int i = 0; i < 8; ++i) f[i] = lfp[i];
        float h[16];
#pragma unroll
        for (int j = 0; j < 16; ++j) {
            float a = lb1[j] + S * lw1[j] + E * lw1[16 + j];
#pragma unroll
            for (int i = 0; i < 8; ++i) a += f[i] * lw1[(2 + i) * 16 + j];
            h[j] = silu_f(a);
        }
#pragma unroll
        for (int j = 0; j < 16; ++j) {
            float a = lb2[j];
#pragma unroll
            for (int i = 0; i < 16; ++i) a += h[i] * lw2[i * 16 + j];
            wc[j * K_ + tid] = w * silu_f(a);
        }
    }
    __syncthreads();

    // ---- A[p] = sum_k wc[p][k] : 16 groups of 16 threads ----
    {
        const int p = tid >> 4, l16 = tid & 15;
        float part = 0.0f;
        for (int k = l16; k < K_; k += 16) part += wc[p * K_ + k];
        red[tid] = part;
        __syncthreads();
        if (l16 < 8) red[tid] += red[tid + 8];
        __syncthreads();
        if (l16 < 4) red[tid] += red[tid + 4];
        __syncthreads();
        if (l16 < 2) red[tid] += red[tid + 2];
        __syncthreads();
        if (l16 == 0) aA[p] = red[tid] + red[tid + 1];
    }
    __syncthreads();

    // ---- phase 3: O + A @ p2_w + p2_b, thread = output dim d ----
    const int d = tid;
    const float* fp = feats + (b * K_) * DIM_ + d;
    float o = 0.0f;
#pragma unroll 8
    for (int k = 0; k < K_; ++k) o += wsh[k] * fp[k * DIM_];
    float a = p2_b[d];
#pragma unroll
    for (int p = 0; p < 16; ++p) a += aA[p] * p2_w[p * DIM_ + d];
    out[(b * T_ + t) * DIM_ + d] = o + a;
}

// ---------------------------------------------------------------------------
extern "C" void kernel_launch(void* const* d_in, const int* in_sizes, int n_in,
                              void* d_out, int out_size, void* d_ws, size_t ws_size,
                              hipStream_t stream) {
    const float* durations = (const float*)d_in[1];
    const float* features  = (const float*)d_in[2];
    const float* conv1_w   = (const float*)d_in[3];
    const float* conv1_b   = (const float*)d_in[4];
    const float* conv2_w   = (const float*)d_in[5];
    const float* conv2_b   = (const float*)d_in[6];
    const float* sw1_w1    = (const float*)d_in[7];
    const float* sw1_b1    = (const float*)d_in[8];
    const float* sw1_w2    = (const float*)d_in[9];
    const float* sw1_b2    = (const float*)d_in[10];
    const float* sw2_w1    = (const float*)d_in[11];
    const float* sw2_b1    = (const float*)d_in[12];
    const float* sw2_w2    = (const float*)d_in[13];
    const float* sw2_b2    = (const float*)d_in[14];
    const float* p1_w      = (const float*)d_in[15];
    const float* p1_b      = (const float*)d_in[16];
    const float* p2_w      = (const float*)d_in[17];
    const float* p2_b      = (const float*)d_in[18];
    float* out = (float*)d_out;

    float* ws     = (float*)d_ws;
    float* starts = ws;                     // B*K
    float* ends   = starts + B_ * K_;       // B*K
    float* left   = ends + B_ * K_;         // B*K*8
    float* right  = left + B_ * K_ * 8;     // B*K*8

    scan_kernel<<<B_, 256, 0, stream>>>(durations, starts, ends);
    conv_kernel<<<B_ * K_, 256, 0, stream>>>(features, conv1_w, conv1_b,
                                             conv2_w, conv2_b, left, right);
    main_kernel<<<dim3(T_, B_), 256, 0, stream>>>(
        features, starts, ends, left, right,
        sw1_w1, sw1_b1, sw1_w2, sw1_b2,
        sw2_w1, sw2_b1, sw2_w2, sw2_b2,
        p1_w, p1_b, p2_w, p2_b, out);
}

// Round 2
// 148.302 us; speedup vs baseline: 1.0249x; 1.0249x over previous
//
#include <hip/hip_runtime.h>
#include <math.h>

#define B_   4
#define K_   200
#define DIM_ 256
#define T_   800
#define TT_  4

__device__ __forceinline__ float silu_f(float x) {
    return x / (1.0f + __expf(-x));
}

// ---------------------------------------------------------------------------
// Prep kernel: fused conv (4 tokens x 16 out-channels per 64-thread block)
// + duration scan (chunk-0 blocks). Grid (50, B).
// ---------------------------------------------------------------------------
__global__ __launch_bounds__(64) void prep_kernel(
        const float* __restrict__ dur,
        const float* __restrict__ feats,
        const float* __restrict__ c1w, const float* __restrict__ c1b,
        const float* __restrict__ c2w, const float* __restrict__ c2b,
        float* __restrict__ starts, float* __restrict__ ends,
        float* __restrict__ left,   float* __restrict__ right) {
    const int b = blockIdx.y, chunk = blockIdx.x, k0 = chunk * 4;
    const int tid = threadIdx.x;

    __shared__ float wT[16][772];   // transposed weights: wT[conv*8+o][tap*256+c]
    __shared__ float fT[6][260];    // feats rows k0-1 .. k0+4 (padded stride)

    for (int i = tid; i < 3 * DIM_ * 8; i += 64) {
        int tc = i >> 3, o = i & 7;
        wT[o][tc]     = c1w[i];
        wT[8 + o][tc] = c2w[i];
    }
    const float4* f4 = (const float4*)feats;
    for (int i = tid; i < 6 * 64; i += 64) {
        int r = i >> 6, c4 = i & 63;
        int kk = k0 - 1 + r;
        float4 v = make_float4(0.f, 0.f, 0.f, 0.f);
        if (kk >= 0 && kk < K_) v = f4[(b * K_ + kk) * 64 + c4];
        *(float4*)&fT[r][c4 * 4] = v;
    }
    __syncthreads();

    const int k = tid >> 4, oc = tid & 15, cv = oc >> 3, o = oc & 7;
    float acc = 0.f;
#pragma unroll
    for (int tap = 0; tap < 3; ++tap) {
#pragma unroll 8
        for (int c = 0; c < DIM_; c += 4) {
            float4 fv = *(const float4*)&fT[k + tap][c];
            float4 wv = *(const float4*)&wT[oc][tap * DIM_ + c];
            acc += fv.x * wv.x + fv.y * wv.y + fv.z * wv.z + fv.w * wv.w;
        }
    }
    int kk = k0 + k;
    if (kk < K_) {
        float bias = cv ? c2b[o] : c1b[o];
        float* dst = cv ? right : left;
        dst[(b * K_ + kk) * 8 + o] = silu_f(acc + bias);
    }

    if (chunk == 0) {
        // inclusive scan of 200 durations: lanes 0..49 own 4 each
        float4 dv = make_float4(0.f, 0.f, 0.f, 0.f);
        if (tid < 50) dv = *(const float4*)&dur[b * K_ + tid * 4];
        float s0 = dv.x, s1 = s0 + dv.y, s2 = s1 + dv.z, s3 = s2 + dv.w;
        float sc = s3;
#pragma unroll
        for (int off = 1; off < 64; off <<= 1) {
            float v = __shfl_up(sc, off);
            if (tid >= off) sc += v;
        }
        float excl = sc - s3;
        if (tid < 50) {
            float4 st = make_float4(excl, excl + s0, excl + s1, excl + s2);
            float4 en = make_float4(excl + s0, excl + s1, excl + s2, excl + s3);
            *(float4*)&starts[b * K_ + tid * 4] = st;
            *(float4*)&ends  [b * K_ + tid * 4] = en;
        }
    }
}

// ---------------------------------------------------------------------------
// Main kernel: TT_=4 frames per block, wave w <-> frame t0+w.
// Lane l owns tokens k = l, l+64, l+128, l+192.
// Grid (T/TT, B), 256 threads.
// ---------------------------------------------------------------------------
__global__ __launch_bounds__(256) void main_kernel(
        const float* __restrict__ feats,
        const float* __restrict__ starts, const float* __restrict__ ends,
        const float* __restrict__ left,   const float* __restrict__ right,
        const float* __restrict__ sw1_w1, const float* __restrict__ sw1_b1,
        const float* __restrict__ sw1_w2, const float* __restrict__ sw1_b2,
        const float* __restrict__ sw2_w1, const float* __restrict__ sw2_b1,
        const float* __restrict__ sw2_w2, const float* __restrict__ sw2_b2,
        const float* __restrict__ p1_w,   const float* __restrict__ p1_b,
        const float* __restrict__ p2_w,   const float* __restrict__ p2_b,
        float* __restrict__ out) {
    const int t0 = blockIdx.x * TT_, b = blockIdx.y;
    const int tid = threadIdx.x, w = tid >> 6, l = tid & 63;
    const int t = t0 + w;

    __shared__ float sS[K_], sE[K_];
    __shared__ float upool[4096];      // phase1/2: lr[k][20]; reduce: red[4][16][64]
    __shared__ float W4[K_][4];        // softmax weights, k-major (b128 broadcast)
    __shared__ float At[16][4];        // A transposed [p][t]
    __shared__ float lw1T[16][12];     // lw1T[j][i] = sw1_w1[i*16+j], pad 12
    __shared__ float lw2T[16][16];     // lw2T[j][i] = sw1_w2[i*16+j]
    __shared__ float lb1s[16], lb2s[16];

    // ---- staging ----
    for (int i = tid; i < K_; i += 256) { sS[i] = starts[b * K_ + i]; sE[i] = ends[b * K_ + i]; }
    const float4* L4 = (const float4*)(left  + b * K_ * 8);
    const float4* R4 = (const float4*)(right + b * K_ * 8);
    for (int j = tid; j < 2 * K_; j += 256) {
        int k = j >> 1, h = j & 1;
        *(float4*)&upool[k * 20 + h * 4]     = L4[j];
        *(float4*)&upool[k * 20 + 8 + h * 4] = R4[j];
    }
    for (int i = tid; i < 160; i += 256) lw1T[i & 15][i >> 4] = sw1_w1[i];
    if (tid < 16) { lw1T[tid][10] = 0.f; lw1T[tid][11] = 0.f; }
    lw2T[tid & 15][tid >> 4] = sw1_w2[tid];
    if (tid < 16) { lb1s[tid] = sw1_b1[tid]; lb2s[tid] = sw1_b2[tid]; }
    __syncthreads();

    // ---- phase 1: logits (sw2 path), small weights in registers ----
    float rw1[20];
#pragma unroll
    for (int i = 0; i < 20; ++i) rw1[i] = sw2_w1[i];
    const float rb10 = sw2_b1[0], rb11 = sw2_b1[1];
    const float rw20 = sw2_w2[0], rw21 = sw2_w2[1], rw22 = sw2_w2[2], rw23 = sw2_w2[3];
    const float rb20 = sw2_b2[0], rb21 = sw2_b2[1];
    const float p10 = p1_w[0], p11 = p1_w[1], p1b0 = p1_b[0];

    float Sv[4], Ev[4], lg[4], fL[4][8];
#pragma unroll
    for (int i = 0; i < 4; ++i) {
        int k = l + 64 * i;
        int kc = (k < K_) ? k : (K_ - 1);
        float S = (float)t - sS[kc];
        float E = sE[kc] - (float)t;
        Sv[i] = S; Ev[i] = E;
        float4 fa = *(const float4*)&upool[kc * 20];
        float4 fb = *(const float4*)&upool[kc * 20 + 4];
        fL[i][0] = fa.x; fL[i][1] = fa.y; fL[i][2] = fa.z; fL[i][3] = fa.w;
        fL[i][4] = fb.x; fL[i][5] = fb.y; fL[i][6] = fb.z; fL[i][7] = fb.w;
        float4 ra = *(const float4*)&upool[kc * 20 + 8];
        float4 rb = *(const float4*)&upool[kc * 20 + 12];
        float h0 = rb10 + S * rw1[0] + E * rw1[2]
                 + ra.x * rw1[4]  + ra.y * rw1[6]  + ra.z * rw1[8]  + ra.w * rw1[10]
                 + rb.x * rw1[12] + rb.y * rw1[14] + rb.z * rw1[16] + rb.w * rw1[18];
        float h1 = rb11 + S * rw1[1] + E * rw1[3]
                 + ra.x * rw1[5]  + ra.y * rw1[7]  + ra.z * rw1[9]  + ra.w * rw1[11]
                 + rb.x * rw1[13] + rb.y * rw1[15] + rb.z * rw1[17] + rb.w * rw1[19];
        h0 = silu_f(h0); h1 = silu_f(h1);
        float g0 = silu_f(rb20 + h0 * rw20 + h1 * rw22);
        float g1 = silu_f(rb21 + h0 * rw21 + h1 * rw23);
        lg[i] = (k < K_) ? (g0 * p10 + g1 * p11 + p1b0) : -1e30f;
    }

    // ---- wave softmax over K ----
    float m = fmaxf(fmaxf(lg[0], lg[1]), fmaxf(lg[2], lg[3]));
#pragma unroll
    for (int off = 32; off > 0; off >>= 1) m = fmaxf(m, __shfl_xor(m, off));
    float e0 = __expf(lg[0] - m), e1 = __expf(lg[1] - m);
    float e2 = __expf(lg[2] - m), e3 = __expf(lg[3] - m);
    float ssum = e0 + e1 + e2 + e3;
#pragma unroll
    for (int off = 32; off > 0; off >>= 1) ssum += __shfl_xor(ssum, off);
    float inv = 1.0f / ssum;
    float wgt[4] = { e0 * inv, e1 * inv, e2 * inv, e3 * inv };
#pragma unroll
    for (int i = 0; i < 4; ++i) { int k = l + 64 * i; if (k < K_) W4[k][w] = wgt[i]; }

    // ---- phase 2: sw1 path with streamed weights ----
    float hmat[4][16];
#pragma unroll
    for (int j = 0; j < 16; ++j) {
        float4 wa = *(const float4*)&lw1T[j][0];
        float4 wb = *(const float4*)&lw1T[j][4];
        float4 wc = *(const float4*)&lw1T[j][8];
        float bj = lb1s[j];
#pragma unroll
        for (int i = 0; i < 4; ++i) {
            float a = bj + Sv[i] * wa.x + Ev[i] * wa.y
                    + fL[i][0] * wa.z + fL[i][1] * wa.w
                    + fL[i][2] * wb.x + fL[i][3] * wb.y
                    + fL[i][4] * wb.z + fL[i][5] * wb.w
                    + fL[i][6] * wc.x + fL[i][7] * wc.y;
            hmat[i][j] = silu_f(a);
        }
    }
    float acc[16];
#pragma unroll
    for (int j = 0; j < 16; ++j) {
        float4 w0 = *(const float4*)&lw2T[j][0];
        float4 w1v = *(const float4*)&lw2T[j][4];
        float4 w2v = *(const float4*)&lw2T[j][8];
        float4 w3v = *(const float4*)&lw2T[j][12];
        float bj = lb2s[j];
        float s = 0.f;
#pragma unroll
        for (int i = 0; i < 4; ++i) {
            float c = bj
                + hmat[i][0]  * w0.x  + hmat[i][1]  * w0.y  + hmat[i][2]  * w0.z  + hmat[i][3]  * w0.w
                + hmat[i][4]  * w1v.x + hmat[i][5]  * w1v.y + hmat[i][6]  * w1v.z + hmat[i][7]  * w1v.w
                + hmat[i][8]  * w2v.x + hmat[i][9]  * w2v.y + hmat[i][10] * w2v.z + hmat[i][11] * w2v.w
                + hmat[i][12] * w3v.x + hmat[i][13] * w3v.y + hmat[i][14] * w3v.z + hmat[i][15] * w3v.w;
            s += wgt[i] * silu_f(c);
        }
        acc[j] = s;
    }

    // ---- reduce acc over lanes via LDS transpose (reuses upool) ----
    __syncthreads();   // all waves done reading lr region
#pragma unroll
    for (int j = 0; j < 16; ++j) upool[(w * 16 + j) * 64 + l] = acc[j];
    __syncthreads();
    {
        int rwv = tid >> 6, rj = (tid >> 2) & 15, rq = tid & 3;
        const float* base = &upool[(rwv * 16 + rj) * 64 + rq * 16];
        float4 a0 = *(const float4*)&base[0];
        float4 a1 = *(const float4*)&base[4];
        float4 a2 = *(const float4*)&base[8];
        float4 a3 = *(const float4*)&base[12];
        float s = a0.x + a0.y + a0.z + a0.w + a1.x + a1.y + a1.z + a1.w
                + a2.x + a2.y + a2.z + a2.w + a3.x + a3.y + a3.z + a3.w;
        s += __shfl_down(s, 1);
        s += __shfl_down(s, 2);
        if (rq == 0) At[rj][rwv] = s;
    }
    __syncthreads();

    // ---- phase 3: O + A @ p2_w + p2_b; thread = output dim d ----
    const float* fp = feats + (size_t)(b * K_) * DIM_ + tid;
    float o0 = 0.f, o1 = 0.f, o2 = 0.f, o3 = 0.f;
#pragma unroll 4
    for (int k = 0; k < K_; ++k) {
        float4 wv = *(const float4*)&W4[k][0];   // broadcast
        float f = fp[(size_t)k * DIM_];
        o0 += wv.x * f; o1 += wv.y * f; o2 += wv.z * f; o3 += wv.w * f;
    }
    float ab = p2_b[tid];
    float a0 = ab, a1 = ab, a2 = ab, a3 = ab;
#pragma unroll
    for (int p = 0; p < 16; ++p) {
        float pw = p2_w[p * DIM_ + tid];
        float4 av = *(const float4*)&At[p][0];   // broadcast
        a0 += av.x * pw; a1 += av.y * pw; a2 += av.z * pw; a3 += av.w * pw;
    }
    float* op = out + ((size_t)b * T_ + t0) * DIM_ + tid;
    op[0 * DIM_] = o0 + a0;
    op[1 * DIM_] = o1 + a1;
    op[2 * DIM_] = o2 + a2;
    op[3 * DIM_] = o3 + a3;
}

// ---------------------------------------------------------------------------
extern "C" void kernel_launch(void* const* d_in, const int* in_sizes, int n_in,
                              void* d_out, int out_size, void* d_ws, size_t ws_size,
                              hipStream_t stream) {
    const float* durations = (const float*)d_in[1];
    const float* features  = (const float*)d_in[2];
    const float* conv1_w   = (const float*)d_in[3];
    const float* conv1_b   = (const float*)d_in[4];
    const float* conv2_w   = (const float*)d_in[5];
    const float* conv2_b   = (const float*)d_in[6];
    const float* sw1_w1    = (const float*)d_in[7];
    const float* sw1_b1    = (const float*)d_in[8];
    const float* sw1_w2    = (const float*)d_in[9];
    const float* sw1_b2    = (const float*)d_in[10];
    const float* sw2_w1    = (const float*)d_in[11];
    const float* sw2_b1    = (const float*)d_in[12];
    const float* sw2_w2    = (const float*)d_in[13];
    const float* sw2_b2    = (const float*)d_in[14];
    const float* p1_w      = (const float*)d_in[15];
    const float* p1_b      = (const float*)d_in[16];
    const float* p2_w      = (const float*)d_in[17];
    const float* p2_b      = (const float*)d_in[18];
    float* out = (float*)d_out;

    float* ws     = (float*)d_ws;
    float* starts = ws;                     // B*K
    float* ends   = starts + B_ * K_;       // B*K
    float* left   = ends + B_ * K_;         // B*K*8
    float* right  = left + B_ * K_ * 8;     // B*K*8

    prep_kernel<<<dim3(50, B_), 64, 0, stream>>>(
        durations, features, conv1_w, conv1_b, conv2_w, conv2_b,
        starts, ends, left, right);
    main_kernel<<<dim3(T_ / TT_, B_), 256, 0, stream>>>(
        features, starts, ends, left, right,
        sw1_w1, sw1_b1, sw1_w2, sw1_b2,
        sw2_w1, sw2_b1, sw2_w2, sw2_b2,
        p1_w, p1_b, p2_w, p2_b, out);
}

// Round 3
// 140.229 us; speedup vs baseline: 1.0839x; 1.0576x over previous
//
#include <hip/hip_runtime.h>
#include <math.h>

#define B_   4
#define K_   200
#define DIM_ 256
#define T_   800

#define S_UP 68          // padded row stride for reduction scratch (bank-safe, 16B-aligned)

__device__ __forceinline__ float silu_f(float x) {
    return x / (1.0f + __expf(-x));
}

// ---------------------------------------------------------------------------
// Prep kernel: conv (16 tokens/block, thread=(token,oc)) + redundant in-block
// scan + per-(b,k) constant folding.  Writes ONLY the const table:
//   cw[b][j][k], j=0: beta0, j=1: beta1, j=2..17: B_j   (SoA, k-fastest)
// Grid (13, B_), 256 threads.
// ---------------------------------------------------------------------------
__global__ __launch_bounds__(256) void prep_kernel(
        const float* __restrict__ dur,
        const float* __restrict__ feats,
        const float* __restrict__ c1w, const float* __restrict__ c1b,
        const float* __restrict__ c2w, const float* __restrict__ c2b,
        const float* __restrict__ sw1_w1, const float* __restrict__ sw1_b1,
        const float* __restrict__ sw2_w1, const float* __restrict__ sw2_b1,
        float* __restrict__ cw) {
    const int b = blockIdx.y, k0 = blockIdx.x * 16;
    const int tid = threadIdx.x, w = tid >> 6, l = tid & 63;

    __shared__ float wT[16][769];       // transposed conv weights
    __shared__ float sSc[K_], sEc[K_];  // scan results
    __shared__ float sfeat[16][16];     // conv outputs (post-silu) for this block

    // stage transposed weights (conv1 rows 0..7, conv2 rows 8..15)
    for (int i = tid; i < 3 * DIM_ * 8; i += 256) {
        int tc = i >> 3, o = i & 7;
        wT[o][tc] = c1w[i];
    }
    for (int i = tid; i < 3 * DIM_ * 8; i += 256) {
        int tc = i >> 3, o = i & 7;
        wT[8 + o][tc] = c2w[i];
    }
    // wave 0: inclusive scan of 200 durations (4 per lane, lanes 0..49)
    if (tid < 64) {
        float4 dv = make_float4(0.f, 0.f, 0.f, 0.f);
        if (tid < 50) dv = *(const float4*)&dur[b * K_ + tid * 4];
        float s0 = dv.x, s1 = s0 + dv.y, s2 = s1 + dv.z, s3 = s2 + dv.w;
        float sc = s3;
#pragma unroll
        for (int off = 1; off < 64; off <<= 1) {
            float v = __shfl_up(sc, off);
            if (tid >= off) sc += v;
        }
        float excl = sc - s3;
        if (tid < 50) {
            *(float4*)&sSc[tid * 4] = make_float4(excl, excl + s0, excl + s1, excl + s2);
            *(float4*)&sEc[tid * 4] = make_float4(excl + s0, excl + s1, excl + s2, excl + s3);
        }
    }
    __syncthreads();

    // conv: thread = (token kl = w*4 + l>>4, oc = l&15)
    const int kl = w * 4 + (l >> 4);
    const int k  = k0 + kl;
    const int oc = l & 15, o = oc & 7;
    const float4* f4 = (const float4*)feats;
    float acc = 0.f;
#pragma unroll
    for (int tap = 0; tap < 3; ++tap) {
        int kk = k + tap - 1;
        bool valid = (kk >= 0 && kk < K_);
        int kc = valid ? kk : 0;
        const float4* fr = f4 + (size_t)(b * K_ + kc) * 64;
        float tacc = 0.f;
#pragma unroll 8
        for (int c4 = 0; c4 < 64; ++c4) {
            float4 fv = fr[c4];
            float4 wv = *(const float4*)&wT[oc][tap * DIM_ + c4 * 4];
            tacc += fv.x * wv.x + fv.y * wv.y + fv.z * wv.z + fv.w * wv.w;
        }
        acc += valid ? tacc : 0.f;
    }
    float bias = (oc < 8) ? c1b[o] : c2b[o];
    sfeat[kl][oc] = silu_f(acc + bias);
    __syncthreads();

    // consts: B_j (16 j's x 16 tokens = 256 threads)
    {
        const int j = tid >> 4, klc = tid & 15;
        const int kk = k0 + klc;
        if (kk < K_) {
            float st = sSc[kk], en = sEc[kk];
            float a = sw1_b1[j] - st * sw1_w1[j] + en * sw1_w1[16 + j];
#pragma unroll
            for (int i = 0; i < 8; ++i) a += sfeat[klc][i] * sw1_w1[(2 + i) * 16 + j];
            cw[(b * 18 + 2 + j) * K_ + kk] = a;
        }
    }
    // consts: beta0 / beta1 (32 threads)
    if (tid < 32) {
        const int which = tid >> 4, klc = tid & 15;
        const int kk = k0 + klc;
        if (kk < K_) {
            float st = sSc[kk], en = sEc[kk];
            float a = sw2_b1[which] - st * sw2_w1[which] + en * sw2_w1[2 + which];
#pragma unroll
            for (int i = 0; i < 8; ++i) a += sfeat[klc][8 + i] * sw2_w1[(2 + i) * 2 + which];
            cw[(b * 18 + which) * K_ + kk] = a;
        }
    }
}

// ---------------------------------------------------------------------------
// Main kernel: 4 frames/block (wave w <-> frame t0+w), grid (T/4, B), 256 thr.
// ---------------------------------------------------------------------------
__global__ __launch_bounds__(256) void main_kernel(
        const float* __restrict__ feats,
        const float* __restrict__ cw,
        const float* __restrict__ sw1_w1, const float* __restrict__ sw1_w2,
        const float* __restrict__ sw1_b2,
        const float* __restrict__ sw2_w1, const float* __restrict__ sw2_w2,
        const float* __restrict__ sw2_b2,
        const float* __restrict__ p1_w,   const float* __restrict__ p1_b,
        const float* __restrict__ p2_w,   const float* __restrict__ p2_b,
        float* __restrict__ out) {
    const int t0 = blockIdx.x * 4, b = blockIdx.y;
    const int tid = threadIdx.x, w = tid >> 6, l = tid & 63;
    const int t = t0 + w;

    __shared__ alignas(16) float cb[18 * K_];          // const table (SoA)
    __shared__ alignas(16) float upool[64 * S_UP];     // reduction scratch
    __shared__ alignas(16) float W4[K_][4];            // softmax weights
    __shared__ alignas(16) float At[16][4];            // A[p][frame]
    __shared__ float lw2T[16][16];                     // lw2T[j][i] = sw1_w2[i*16+j]
    __shared__ float lb2s[16];

    // ---- stage const table + small weights ----
    {
        const float4* cg4 = (const float4*)(cw + b * 18 * K_);
        float4* cb4 = (float4*)cb;
        for (int i = tid; i < 18 * K_ / 4; i += 256) cb4[i] = cg4[i];
    }
    lw2T[tid & 15][tid >> 4] = sw1_w2[tid];
    if (tid < 16) lb2s[tid] = sw1_b2[tid];
    __syncthreads();

    const float tf = (float)t;
    const float a0 = sw2_w1[0] - sw2_w1[2], a1 = sw2_w1[1] - sw2_w1[3];
    const float rw20 = sw2_w2[0], rw21 = sw2_w2[1], rw22 = sw2_w2[2], rw23 = sw2_w2[3];
    const float rb20 = sw2_b2[0], rb21 = sw2_b2[1];
    const float p10 = p1_w[0], p11 = p1_w[1], p1b0 = p1_b[0];

    // ---- phase 1: logits + wave softmax ----
    float lg[4];
#pragma unroll
    for (int i = 0; i < 4; ++i) {
        int k = l + 64 * i;
        int kc = (k < K_) ? k : (K_ - 1);
        float h0 = silu_f(fmaf(a0, tf, cb[0 * K_ + kc]));
        float h1 = silu_f(fmaf(a1, tf, cb[1 * K_ + kc]));
        float g0 = silu_f(rb20 + h0 * rw20 + h1 * rw22);
        float g1 = silu_f(rb21 + h0 * rw21 + h1 * rw23);
        lg[i] = (k < K_) ? (g0 * p10 + g1 * p11 + p1b0) : -1e30f;
    }
    float m = fmaxf(fmaxf(lg[0], lg[1]), fmaxf(lg[2], lg[3]));
#pragma unroll
    for (int off = 32; off > 0; off >>= 1) m = fmaxf(m, __shfl_xor(m, off));
    float e0 = __expf(lg[0] - m), e1 = __expf(lg[1] - m);
    float e2 = __expf(lg[2] - m), e3 = __expf(lg[3] - m);
    float ssum = e0 + e1 + e2 + e3;
#pragma unroll
    for (int off = 32; off > 0; off >>= 1) ssum += __shfl_xor(ssum, off);
    float inv = 1.0f / ssum;
    float wgt[4] = { e0 * inv, e1 * inv, e2 * inv, e3 * inv };
#pragma unroll
    for (int i = 0; i < 4; ++i) { int k = l + 64 * i; if (k < K_) W4[k][w] = wgt[i]; }

    // ---- phase 2: sw1 path (L1 = 1 FMA via precomputed consts) ----
    float ajt[16];
#pragma unroll
    for (int j = 0; j < 16; ++j) ajt[j] = (sw1_w1[j] - sw1_w1[16 + j]) * tf;

    float hmat[4][16];
#pragma unroll
    for (int j = 0; j < 16; ++j) {
#pragma unroll
        for (int i = 0; i < 4; ++i) {
            int k = l + 64 * i;
            int kc = (k < K_) ? k : (K_ - 1);
            hmat[i][j] = silu_f(ajt[j] + cb[(2 + j) * K_ + kc]);
        }
    }
    float acc[16];
#pragma unroll
    for (int j = 0; j < 16; ++j) {
        float4 w0 = *(const float4*)&lw2T[j][0];
        float4 w1v = *(const float4*)&lw2T[j][4];
        float4 w2v = *(const float4*)&lw2T[j][8];
        float4 w3v = *(const float4*)&lw2T[j][12];
        float bj = lb2s[j];
        float s = 0.f;
#pragma unroll
        for (int i = 0; i < 4; ++i) {
            float c = bj
                + hmat[i][0]  * w0.x  + hmat[i][1]  * w0.y  + hmat[i][2]  * w0.z  + hmat[i][3]  * w0.w
                + hmat[i][4]  * w1v.x + hmat[i][5]  * w1v.y + hmat[i][6]  * w1v.z + hmat[i][7]  * w1v.w
                + hmat[i][8]  * w2v.x + hmat[i][9]  * w2v.y + hmat[i][10] * w2v.z + hmat[i][11] * w2v.w
                + hmat[i][12] * w3v.x + hmat[i][13] * w3v.y + hmat[i][14] * w3v.z + hmat[i][15] * w3v.w;
            s += wgt[i] * silu_f(c);
        }
        acc[j] = s;
    }

    // ---- A-reduce: transpose through upool -> At[16][4] ----
#pragma unroll
    for (int j = 0; j < 16; ++j) upool[(w * 16 + j) * S_UP + l] = acc[j];
    __syncthreads();
    {
        int rwv = tid >> 6, rj = (tid >> 2) & 15, rq = tid & 3;
        const float* base = &upool[(rwv * 16 + rj) * S_UP + rq * 16];
        float4 b0 = *(const float4*)&base[0];
        float4 b1 = *(const float4*)&base[4];
        float4 b2 = *(const float4*)&base[8];
        float4 b3 = *(const float4*)&base[12];
        float s = b0.x + b0.y + b0.z + b0.w + b1.x + b1.y + b1.z + b1.w
                + b2.x + b2.y + b2.z + b2.w + b3.x + b3.y + b3.z + b3.w;
        s += __shfl_down(s, 1);
        s += __shfl_down(s, 2);
        if (rq == 0) At[rj][rwv] = s;
    }
    __syncthreads();   // At ready; W4 (phase 1) also visible to all waves

    // ---- phase 3: O partials. wave w covers k in [50w, 50w+50), lane l ->
    //      d = 4l..4l+3 (float4).  po[f][q] accumulators. ----
    {
        const float4* fB4 = (const float4*)(feats + (size_t)b * K_ * DIM_);
        float4 po[4];
#pragma unroll
        for (int f = 0; f < 4; ++f) po[f] = make_float4(0.f, 0.f, 0.f, 0.f);
        const int kb = w * 50;
        for (int kk = 0; kk < 50; ++kk) {
            int k = kb + kk;
            float4 wv = *(const float4*)&W4[k][0];      // broadcast
            float4 fv = fB4[k * 64 + l];
            po[0].x += wv.x * fv.x; po[0].y += wv.x * fv.y; po[0].z += wv.x * fv.z; po[0].w += wv.x * fv.w;
            po[1].x += wv.y * fv.x; po[1].y += wv.y * fv.y; po[1].z += wv.y * fv.z; po[1].w += wv.y * fv.w;
            po[2].x += wv.z * fv.x; po[2].y += wv.z * fv.y; po[2].z += wv.z * fv.z; po[2].w += wv.z * fv.w;
            po[3].x += wv.w * fv.x; po[3].y += wv.w * fv.y; po[3].z += wv.w * fv.z; po[3].w += wv.w * fv.w;
        }
        // partials: upool[(w*16 + f*4 + q) * S_UP + l]
#pragma unroll
        for (int f = 0; f < 4; ++f) {
            upool[(w * 16 + f * 4 + 0) * S_UP + l] = po[f].x;
            upool[(w * 16 + f * 4 + 1) * S_UP + l] = po[f].y;
            upool[(w * 16 + f * 4 + 2) * S_UP + l] = po[f].z;
            upool[(w * 16 + f * 4 + 3) * S_UP + l] = po[f].w;
        }
    }
    __syncthreads();

    // ---- final: thread = d = tid; owner lane l0 = d>>2, comp q = d&3 ----
    {
        const int d = tid, l0 = d >> 2, q = d & 3;
        float v0 = 0.f, v1 = 0.f, v2 = 0.f, v3 = 0.f;
#pragma unroll
        for (int ww = 0; ww < 4; ++ww) {
            v0 += upool[(ww * 16 + 0 * 4 + q) * S_UP + l0];
            v1 += upool[(ww * 16 + 1 * 4 + q) * S_UP + l0];
            v2 += upool[(ww * 16 + 2 * 4 + q) * S_UP + l0];
            v3 += upool[(ww * 16 + 3 * 4 + q) * S_UP + l0];
        }
        float ab = p2_b[d];
        v0 += ab; v1 += ab; v2 += ab; v3 += ab;
#pragma unroll
        for (int p = 0; p < 16; ++p) {
            float pw = p2_w[p * DIM_ + d];
            float4 av = *(const float4*)&At[p][0];      // broadcast
            v0 += av.x * pw; v1 += av.y * pw; v2 += av.z * pw; v3 += av.w * pw;
        }
        float* op = out + ((size_t)b * T_ + t0) * DIM_ + d;
        op[0 * DIM_] = v0;
        op[1 * DIM_] = v1;
        op[2 * DIM_] = v2;
        op[3 * DIM_] = v3;
    }
}

// ---------------------------------------------------------------------------
extern "C" void kernel_launch(void* const* d_in, const int* in_sizes, int n_in,
                              void* d_out, int out_size, void* d_ws, size_t ws_size,
                              hipStream_t stream) {
    const float* durations = (const float*)d_in[1];
    const float* features  = (const float*)d_in[2];
    const float* conv1_w   = (const float*)d_in[3];
    const float* conv1_b   = (const float*)d_in[4];
    const float* conv2_w   = (const float*)d_in[5];
    const float* conv2_b   = (const float*)d_in[6];
    const float* sw1_w1    = (const float*)d_in[7];
    const float* sw1_b1    = (const float*)d_in[8];
    const float* sw1_w2    = (const float*)d_in[9];
    const float* sw1_b2    = (const float*)d_in[10];
    const float* sw2_w1    = (const float*)d_in[11];
    const float* sw2_b1    = (const float*)d_in[12];
    const float* sw2_w2    = (const float*)d_in[13];
    const float* sw2_b2    = (const float*)d_in[14];
    const float* p1_w      = (const float*)d_in[15];
    const float* p1_b      = (const float*)d_in[16];
    const float* p2_w      = (const float*)d_in[17];
    const float* p2_b      = (const float*)d_in[18];
    float* out = (float*)d_out;

    float* cw = (float*)d_ws;   // [B][18][K] const table

    prep_kernel<<<dim3(13, B_), 256, 0, stream>>>(
        durations, features, conv1_w, conv1_b, conv2_w, conv2_b,
        sw1_w1, sw1_b1, sw2_w1, sw2_b1, cw);
    main_kernel<<<dim3(T_ / 4, B_), 256, 0, stream>>>(
        features, cw,
        sw1_w1, sw1_w2, sw1_b2,
        sw2_w1, sw2_w2, sw2_b2,
        p1_w, p1_b, p2_w, p2_b, out);
}

// Round 4
// 130.204 us; speedup vs baseline: 1.1673x; 1.0770x over previous
//
#include <hip/hip_runtime.h>
#include <math.h>

#define B_   4
#define K_   200
#define DIM_ 256
#define T_   800

#define S_UP 68   // padded row stride (16B-aligned, ~2-way banks at worst)

__device__ __forceinline__ float silu_f(float x) {
    return x / (1.0f + __expf(-x));
}

// ---------------------------------------------------------------------------
// Prep: conv (wave=token, lane=4-ch slice, coalesced) + scan + const folding.
// Writes cw[b][j][k]: j=0 beta0, j=1 beta1, j=2..17 B_j  (SoA, k-fastest).
// Grid (50, B_), 256 threads.
// ---------------------------------------------------------------------------
__global__ __launch_bounds__(256) void prep_kernel(
        const float* __restrict__ dur,
        const float* __restrict__ feats,
        const float* __restrict__ c1w, const float* __restrict__ c1b,
        const float* __restrict__ c2w, const float* __restrict__ c2b,
        const float* __restrict__ sw1_w1, const float* __restrict__ sw1_b1,
        const float* __restrict__ sw2_w1, const float* __restrict__ sw2_b1,
        float* __restrict__ cw) {
    const int b = blockIdx.y, k0 = blockIdx.x * 4;
    const int tid = threadIdx.x, w = tid >> 6, l = tid & 63;

    __shared__ float wT[16][772];        // wT[oc][tap*256+c]  (oc>=8 -> conv2)
    __shared__ float red[64][S_UP];      // cross-lane reduce scratch
    __shared__ float sSc[K_], sEc[K_];
    __shared__ float sfeat[4][16];       // conv outputs (post-silu)

    // stage transposed conv weights (reads coalesced)
    for (int i = tid; i < 3 * DIM_ * 8; i += 256) {
        int tc = i >> 3, o = i & 7;
        wT[o][tc]     = c1w[i];
        wT[8 + o][tc] = c2w[i];
    }
    // wave 0: inclusive scan of 200 durations
    if (tid < 64) {
        float4 dv = make_float4(0.f, 0.f, 0.f, 0.f);
        if (tid < 50) dv = *(const float4*)&dur[b * K_ + tid * 4];
        float s0 = dv.x, s1 = s0 + dv.y, s2 = s1 + dv.z, s3 = s2 + dv.w;
        float sc = s3;
#pragma unroll
        for (int off = 1; off < 64; off <<= 1) {
            float v = __shfl_up(sc, off);
            if (tid >= off) sc += v;
        }
        float excl = sc - s3;
        if (tid < 50) {
            *(float4*)&sSc[tid * 4] = make_float4(excl, excl + s0, excl + s1, excl + s2);
            *(float4*)&sEc[tid * 4] = make_float4(excl + s0, excl + s1, excl + s2, excl + s3);
        }
    }
    __syncthreads();

    // conv: wave w owns token k0+w; lane l owns channels 4l..4l+3
    {
        const int k = k0 + w;
        const float4* f4 = (const float4*)feats;
        float4 fv[3];
#pragma unroll
        for (int tap = 0; tap < 3; ++tap) {
            int kk = k - 1 + tap;
            bool valid = (kk >= 0 && kk < K_);
            int kc = valid ? kk : 0;
            float4 v = f4[(size_t)(b * K_ + kc) * 64 + l];
            fv[tap] = valid ? v : make_float4(0.f, 0.f, 0.f, 0.f);
        }
        float acc[16];
#pragma unroll
        for (int oc = 0; oc < 16; ++oc) acc[oc] = 0.f;
#pragma unroll
        for (int tap = 0; tap < 3; ++tap) {
#pragma unroll
            for (int oc = 0; oc < 16; ++oc) {
                float4 wv = *(const float4*)&wT[oc][tap * DIM_ + 4 * l];
                acc[oc] += fv[tap].x * wv.x + fv[tap].y * wv.y
                         + fv[tap].z * wv.z + fv[tap].w * wv.w;
            }
        }
#pragma unroll
        for (int oc = 0; oc < 16; ++oc) red[w * 16 + oc][l] = acc[oc];
    }
    __syncthreads();
    // reduce 64 lanes -> sfeat
    {
        const int rwv = tid >> 6, oc = (tid >> 2) & 15, rq = tid & 3;
        const float* base = &red[rwv * 16 + oc][rq * 16];
        float4 b0 = *(const float4*)&base[0];
        float4 b1 = *(const float4*)&base[4];
        float4 b2 = *(const float4*)&base[8];
        float4 b3 = *(const float4*)&base[12];
        float s = b0.x + b0.y + b0.z + b0.w + b1.x + b1.y + b1.z + b1.w
                + b2.x + b2.y + b2.z + b2.w + b3.x + b3.y + b3.z + b3.w;
        s += __shfl_down(s, 1);
        s += __shfl_down(s, 2);
        if (rq == 0) {
            float bias = (oc < 8) ? c1b[oc] : c2b[oc & 7];
            sfeat[rwv][oc] = silu_f(s + bias);
        }
    }
    __syncthreads();

    // consts for this block's 4 tokens
    if (tid < 64) {                       // B_j: j = tid>>2, token = tid&3
        const int j = tid >> 2, klc = tid & 3, kk = k0 + klc;
        float st = sSc[kk], en = sEc[kk];
        float a = sw1_b1[j] - st * sw1_w1[j] + en * sw1_w1[16 + j];
#pragma unroll
        for (int i = 0; i < 8; ++i) a += sfeat[klc][i] * sw1_w1[(2 + i) * 16 + j];
        cw[(b * 18 + 2 + j) * K_ + kk] = a;
    } else if (tid < 72) {                // betas
        const int idx = tid - 64, which = idx >> 2, klc = idx & 3, kk = k0 + klc;
        float st = sSc[kk], en = sEc[kk];
        float a = sw2_b1[which] - st * sw2_w1[which] + en * sw2_w1[2 + which];
#pragma unroll
        for (int i = 0; i < 8; ++i) a += sfeat[klc][8 + i] * sw2_w1[(2 + i) * 2 + which];
        cw[(b * 18 + which) * K_ + kk] = a;
    }
}

// ---------------------------------------------------------------------------
// Main: 4 frames/block (wave w <-> frame t0+w), grid (T/4, B), 256 thr.
// Consts read straight from L2 into registers; 3 barriers total.
// ---------------------------------------------------------------------------
__global__ __launch_bounds__(256, 3) void main_kernel(
        const float* __restrict__ feats,
        const float* __restrict__ cw,
        const float* __restrict__ sw1_w1, const float* __restrict__ sw1_w2,
        const float* __restrict__ sw1_b2,
        const float* __restrict__ sw2_w1, const float* __restrict__ sw2_w2,
        const float* __restrict__ sw2_b2,
        const float* __restrict__ p1_w,   const float* __restrict__ p1_b,
        const float* __restrict__ p2_w,   const float* __restrict__ p2_b,
        float* __restrict__ out) {
    const int t0 = blockIdx.x * 4, b = blockIdx.y;
    const int tid = threadIdx.x, w = tid >> 6, l = tid & 63;
    const int t = t0 + w;

    __shared__ alignas(16) float upool[128 * S_UP];  // rows 0..63: A-partials, 64..127: O-partials
    __shared__ alignas(16) float W4[K_][4];
    __shared__ alignas(16) float At[16][4];
    __shared__ float lw2T[16][16];
    __shared__ float lb2s[16];

    lw2T[tid & 15][tid >> 4] = sw1_w2[tid];
    if (tid < 16) lb2s[tid] = sw1_b2[tid];

    // ---- issue all const loads (coalesced, L2) ----
    const float* cbg = cw + b * 18 * K_;
    int kc[4];
#pragma unroll
    for (int i = 0; i < 4; ++i) { int k = l + 64 * i; kc[i] = (k < K_) ? k : (K_ - 1); }
    float Bv[4][16];
#pragma unroll
    for (int j = 0; j < 16; ++j)
#pragma unroll
        for (int i = 0; i < 4; ++i) Bv[i][j] = cbg[(2 + j) * K_ + kc[i]];
    float c0[4], c1[4];
#pragma unroll
    for (int i = 0; i < 4; ++i) { c0[i] = cbg[kc[i]]; c1[i] = cbg[K_ + kc[i]]; }

    __syncthreads();   // barrier 0: lw2T staged

    const float tf = (float)t;
    const float a0 = sw2_w1[0] - sw2_w1[2], a1 = sw2_w1[1] - sw2_w1[3];
    const float rw20 = sw2_w2[0], rw21 = sw2_w2[1], rw22 = sw2_w2[2], rw23 = sw2_w2[3];
    const float rb20 = sw2_b2[0], rb21 = sw2_b2[1];
    const float p10 = p1_w[0], p11 = p1_w[1], p1b0 = p1_b[0];

    // ---- phase 1: logits + wave softmax ----
    float lg[4];
#pragma unroll
    for (int i = 0; i < 4; ++i) {
        float h0 = silu_f(fmaf(a0, tf, c0[i]));
        float h1 = silu_f(fmaf(a1, tf, c1[i]));
        float g0 = silu_f(rb20 + h0 * rw20 + h1 * rw22);
        float g1 = silu_f(rb21 + h0 * rw21 + h1 * rw23);
        lg[i] = (l + 64 * i < K_) ? (g0 * p10 + g1 * p11 + p1b0) : -1e30f;
    }
    float m = fmaxf(fmaxf(lg[0], lg[1]), fmaxf(lg[2], lg[3]));
#pragma unroll
    for (int off = 32; off > 0; off >>= 1) m = fmaxf(m, __shfl_xor(m, off));
    float e0 = __expf(lg[0] - m), e1 = __expf(lg[1] - m);
    float e2 = __expf(lg[2] - m), e3 = __expf(lg[3] - m);
    float ssum = e0 + e1 + e2 + e3;
#pragma unroll
    for (int off = 32; off > 0; off >>= 1) ssum += __shfl_xor(ssum, off);
    float inv = 1.0f / ssum;
    float wgt[4] = { e0 * inv, e1 * inv, e2 * inv, e3 * inv };
#pragma unroll
    for (int i = 0; i < 4; ++i) { int k = l + 64 * i; if (k < K_) W4[k][w] = wgt[i]; }

    // ---- prefetch first 8 phase-3 feats tiles (hides L2 latency under phase 2) ----
    const int kb = w * 50;
    const float4* fB4 = (const float4*)(feats + (size_t)b * K_ * DIM_);
    float4 pf[8];
#pragma unroll
    for (int q = 0; q < 8; ++q) pf[q] = fB4[(size_t)(kb + q) * 64 + l];

    // ---- phase 2: hmat = silu(ajt + B), acc = sum_i wgt*silu(hmat @ lw2) ----
    float ajt[16];
#pragma unroll
    for (int j = 0; j < 16; ++j) ajt[j] = (sw1_w1[j] - sw1_w1[16 + j]) * tf;
    float hmat[4][16];
#pragma unroll
    for (int j = 0; j < 16; ++j)
#pragma unroll
        for (int i = 0; i < 4; ++i) hmat[i][j] = silu_f(ajt[j] + Bv[i][j]);
    float acc[16];
#pragma unroll
    for (int j = 0; j < 16; ++j) {
        float4 w0 = *(const float4*)&lw2T[j][0];
        float4 w1v = *(const float4*)&lw2T[j][4];
        float4 w2v = *(const float4*)&lw2T[j][8];
        float4 w3v = *(const float4*)&lw2T[j][12];
        float bj = lb2s[j];
        float s = 0.f;
#pragma unroll
        for (int i = 0; i < 4; ++i) {
            float c = bj
                + hmat[i][0]  * w0.x  + hmat[i][1]  * w0.y  + hmat[i][2]  * w0.z  + hmat[i][3]  * w0.w
                + hmat[i][4]  * w1v.x + hmat[i][5]  * w1v.y + hmat[i][6]  * w1v.z + hmat[i][7]  * w1v.w
                + hmat[i][8]  * w2v.x + hmat[i][9]  * w2v.y + hmat[i][10] * w2v.z + hmat[i][11] * w2v.w
                + hmat[i][12] * w3v.x + hmat[i][13] * w3v.y + hmat[i][14] * w3v.z + hmat[i][15] * w3v.w;
            s += wgt[i] * silu_f(c);
        }
        acc[j] = s;
    }
#pragma unroll
    for (int j = 0; j < 16; ++j) upool[(w * 16 + j) * S_UP + l] = acc[j];

    __syncthreads();   // barrier 1: A-partials + W4 visible

    // ---- A transpose-reduce (reads rows 0..63; phase 3 writes rows 64..127) ----
    {
        const int rwv = tid >> 6, rj = (tid >> 2) & 15, rq = tid & 3;
        const float* base = &upool[(rwv * 16 + rj) * S_UP + rq * 16];
        float4 b0 = *(const float4*)&base[0];
        float4 b1 = *(const float4*)&base[4];
        float4 b2 = *(const float4*)&base[8];
        float4 b3 = *(const float4*)&base[12];
        float s = b0.x + b0.y + b0.z + b0.w + b1.x + b1.y + b1.z + b1.w
                + b2.x + b2.y + b2.z + b2.w + b3.x + b3.y + b3.z + b3.w;
        s += __shfl_down(s, 1);
        s += __shfl_down(s, 2);
        if (rq == 0) At[rj][rwv] = s;
    }

    // ---- phase 3: O partials, wave w covers k in [50w, 50w+50) ----
    {
        float4 po[4];
#pragma unroll
        for (int f = 0; f < 4; ++f) po[f] = make_float4(0.f, 0.f, 0.f, 0.f);
#pragma unroll
        for (int kk = 0; kk < 8; ++kk) {
            float4 wv = *(const float4*)&W4[kb + kk][0];
            float4 fv = pf[kk];
            po[0].x += wv.x * fv.x; po[0].y += wv.x * fv.y; po[0].z += wv.x * fv.z; po[0].w += wv.x * fv.w;
            po[1].x += wv.y * fv.x; po[1].y += wv.y * fv.y; po[1].z += wv.y * fv.z; po[1].w += wv.y * fv.w;
            po[2].x += wv.z * fv.x; po[2].y += wv.z * fv.y; po[2].z += wv.z * fv.z; po[2].w += wv.z * fv.w;
            po[3].x += wv.w * fv.x; po[3].y += wv.w * fv.y; po[3].z += wv.w * fv.z; po[3].w += wv.w * fv.w;
        }
#pragma unroll 6
        for (int kk = 8; kk < 50; ++kk) {
            float4 wv = *(const float4*)&W4[kb + kk][0];
            float4 fv = fB4[(size_t)(kb + kk) * 64 + l];
            po[0].x += wv.x * fv.x; po[0].y += wv.x * fv.y; po[0].z += wv.x * fv.z; po[0].w += wv.x * fv.w;
            po[1].x += wv.y * fv.x; po[1].y += wv.y * fv.y; po[1].z += wv.y * fv.z; po[1].w += wv.y * fv.w;
            po[2].x += wv.z * fv.x; po[2].y += wv.z * fv.y; po[2].z += wv.z * fv.z; po[2].w += wv.z * fv.w;
            po[3].x += wv.w * fv.x; po[3].y += wv.w * fv.y; po[3].z += wv.w * fv.z; po[3].w += wv.w * fv.w;
        }
#pragma unroll
        for (int f = 0; f < 4; ++f) {
            upool[(64 + w * 16 + f * 4 + 0) * S_UP + l] = po[f].x;
            upool[(64 + w * 16 + f * 4 + 1) * S_UP + l] = po[f].y;
            upool[(64 + w * 16 + f * 4 + 2) * S_UP + l] = po[f].z;
            upool[(64 + w * 16 + f * 4 + 3) * S_UP + l] = po[f].w;
        }
    }
    __syncthreads();   // barrier 2: O-partials + At visible

    // ---- final: thread = d ----
    {
        const int d = tid, l0 = d >> 2, q = d & 3;
        float v0 = 0.f, v1 = 0.f, v2 = 0.f, v3 = 0.f;
#pragma unroll
        for (int ww = 0; ww < 4; ++ww) {
            v0 += upool[(64 + ww * 16 + 0 * 4 + q) * S_UP + l0];
            v1 += upool[(64 + ww * 16 + 1 * 4 + q) * S_UP + l0];
            v2 += upool[(64 + ww * 16 + 2 * 4 + q) * S_UP + l0];
            v3 += upool[(64 + ww * 16 + 3 * 4 + q) * S_UP + l0];
        }
        float ab = p2_b[d];
        v0 += ab; v1 += ab; v2 += ab; v3 += ab;
#pragma unroll
        for (int p = 0; p < 16; ++p) {
            float pw = p2_w[p * DIM_ + d];
            float4 av = *(const float4*)&At[p][0];
            v0 += av.x * pw; v1 += av.y * pw; v2 += av.z * pw; v3 += av.w * pw;
        }
        float* op = out + ((size_t)b * T_ + t0) * DIM_ + d;
        op[0 * DIM_] = v0;
        op[1 * DIM_] = v1;
        op[2 * DIM_] = v2;
        op[3 * DIM_] = v3;
    }
}

// ---------------------------------------------------------------------------
extern "C" void kernel_launch(void* const* d_in, const int* in_sizes, int n_in,
                              void* d_out, int out_size, void* d_ws, size_t ws_size,
                              hipStream_t stream) {
    const float* durations = (const float*)d_in[1];
    const float* features  = (const float*)d_in[2];
    const float* conv1_w   = (const float*)d_in[3];
    const float* conv1_b   = (const float*)d_in[4];
    const float* conv2_w   = (const float*)d_in[5];
    const float* conv2_b   = (const float*)d_in[6];
    const float* sw1_w1    = (const float*)d_in[7];
    const float* sw1_b1    = (const float*)d_in[8];
    const float* sw1_w2    = (const float*)d_in[9];
    const float* sw1_b2    = (const float*)d_in[10];
    const float* sw2_w1    = (const float*)d_in[11];
    const float* sw2_b1    = (const float*)d_in[12];
    const float* sw2_w2    = (const float*)d_in[13];
    const float* sw2_b2    = (const float*)d_in[14];
    const float* p1_w      = (const float*)d_in[15];
    const float* p1_b      = (const float*)d_in[16];
    const float* p2_w      = (const float*)d_in[17];
    const float* p2_b      = (const float*)d_in[18];
    float* out = (float*)d_out;

    float* cw = (float*)d_ws;   // [B][18][K]

    prep_kernel<<<dim3(50, B_), 256, 0, stream>>>(
        durations, features, conv1_w, conv1_b, conv2_w, conv2_b,
        sw1_w1, sw1_b1, sw2_w1, sw2_b1, cw);
    main_kernel<<<dim3(T_ / 4, B_), 256, 0, stream>>>(
        features, cw,
        sw1_w1, sw1_w2, sw1_b2,
        sw2_w1, sw2_w2, sw2_b2,
        p1_w, p1_b, p2_w, p2_b, out);
}